// Round 11
// baseline (218.788 us; speedup 1.0000x reference)
//
#include <hip/hip_runtime.h>
#include <hip/hip_bf16.h>

typedef short  short4v __attribute__((ext_vector_type(4)));
typedef short  short8v __attribute__((ext_vector_type(8)));
typedef float  float4v __attribute__((ext_vector_type(4)));

#define N_LQ 1024
#define N_LK 1024
#define N_B  4
#define N_E  1024
#define N_H  16
#define N_DH 64

#define EXP2(x) __builtin_amdgcn_exp2f(x)

__device__ __forceinline__ unsigned short f2bf(float f){
  unsigned int u = __float_as_uint(f);
  u += 0x7fffu + ((u >> 16) & 1u);          // round-to-nearest-even
  return (unsigned short)(u >> 16);
}

__device__ __forceinline__ ushort f2bf_n(float f){
  __hip_bfloat16 h = __float2bfloat16(f);
  return *reinterpret_cast<ushort*>(&h);
}

// permuted position of k-offset d within a 64-col row (k-blocks of 32):
// fragment chunk 8g holds k = 4g + (e&3) + 16*(e>>2)  -> contiguous b128 frags
__device__ __forceinline__ int permd(int d){
  return (d & 32) + 8*((d>>2)&3) + (d&3) + 4*((d>>4)&1);
}

__device__ __forceinline__ void gload_lds16(const void* g, void* lds){
  __builtin_amdgcn_global_load_lds(
      (const __attribute__((address_space(1))) unsigned int*)g,
      (__attribute__((address_space(3))) unsigned int*)lds, 16, 0, 0);
}

// Stage a (ROUNDS*32) x 64 bf16 tile (k-permuted layout) into linear LDS,
// T2 XOR-swizzle applied on the GLOBAL side at 16B-chunk granularity.
template<int ROUNDS>
__device__ __forceinline__ void stage_tile(const ushort* src, int lda, ushort* ldsbase,
                                           int wave, int lane){
  const int rl = lane >> 3;
  const int ch = lane & 7;
#pragma unroll
  for (int r = 0; r < ROUNDS; ++r){
    const int row = r*32 + wave*8 + rl;
    const int c   = ch ^ (row & 7);
    gload_lds16(src + (size_t)row*lda + c*8, ldsbase + (size_t)(r*32 + wave*8)*64);
  }
}

// One contiguous b128 fragment read from the swizzled k-permuted LDS tile.
__device__ __forceinline__ short8v ldfrag_swz(const ushort* tile, int row, int g, int ks){
  const int ch = ((ks >> 3) + g) ^ (row & 7);
  return *(const short8v*)(tile + row*64 + ch*8);
}

// ---- convert all five f32 inputs to bf16, k-permuted, in one pass ----------
__global__ __launch_bounds__(256) void cvt_all(
    const float* __restrict__ q, const float* __restrict__ k,
    const float* __restrict__ wq, const float* __restrict__ wkv,
    const float* __restrict__ wo, ushort* __restrict__ dst){
  const size_t i = ((size_t)blockIdx.x*256 + threadIdx.x)*8;
  const float* s; size_t o;
  if      (i <  4194304ull){ s = q;   o = i; }
  else if (i <  8388608ull){ s = k;   o = i -  4194304ull; }
  else if (i <  9437184ull){ s = wq;  o = i -  8388608ull; }
  else if (i < 11534336ull){ s = wkv; o = i -  9437184ull; }
  else                     { s = wo;  o = i - 11534336ull; }
  const size_t base = o & ~(size_t)31;
  const int g = (int)((o >> 3) & 3);
  float4v a = *(const float4v*)(s + base + 4*g);
  float4v b = *(const float4v*)(s + base + 4*g + 16);
  short8v r;
  r[0]=(short)f2bf(a[0]); r[1]=(short)f2bf(a[1]); r[2]=(short)f2bf(a[2]); r[3]=(short)f2bf(a[3]);
  r[4]=(short)f2bf(b[0]); r[5]=(short)f2bf(b[1]); r[6]=(short)f2bf(b[2]); r[7]=(short)f2bf(b[3]);
  *(short8v*)(dst + i) = r;
}

// ---- GEMM:  C[m][n] = sum_k A[m][k]*W[n][k], k-permuted inputs -------------
// MODE 0: fused QKV (panel<8 -> Q-proj, else KV-proj). MODE 2: out-proj.
template<int MODE, int BN>
__global__ __launch_bounds__(256) void gemm_k(
    const ushort* __restrict__ A0, const ushort* __restrict__ A1,
    const ushort* __restrict__ W0, const ushort* __restrict__ W1,
    void* __restrict__ O0, void* __restrict__ O1, void* __restrict__ O2,
    int K){
  __shared__ ushort As[128*64];
  __shared__ ushort Bs[BN*64];
  constexpr int NT = BN/32;
  const int tid = threadIdx.x, lane = tid & 63, wave = tid >> 6;
  const int g = lane >> 4, c = lane & 15;
  const int wm = wave >> 1, wn = wave & 1;

  // T1 XCD-aware swizzle (grid count divisible by 8)
  const int nx = gridDim.x;
  const int lin = blockIdx.y * nx + blockIdx.x;
  const int cpx = (nx * gridDim.y) >> 3;
  const int swz = (lin & 7) * cpx + (lin >> 3);
  const int bx = swz % nx, by = swz / nx;
  const int m0 = bx * 128;

  const ushort* A; const ushort* W; int n0; bool isQ = true;
  if (MODE == 0){
    isQ = by < 8;
    A = isQ ? A0 : A1; W = isQ ? W0 : W1;
    n0 = isQ ? by*128 : (by-8)*128;
  } else {
    A = A0; W = W0; n0 = by * BN;
  }

  float4v acc[4][NT];
#pragma unroll
  for (int i=0;i<4;i++)
#pragma unroll
  for (int j=0;j<NT;j++){ acc[i][j][0]=0.f; acc[i][j][1]=0.f; acc[i][j][2]=0.f; acc[i][j][3]=0.f; }

  for (int k0 = 0; k0 < K; k0 += 64){
    __syncthreads();
    stage_tile<4>     (A + (size_t)m0*K + k0, K, As, wave, lane);
    stage_tile<BN/32> (W + (size_t)n0*K + k0, K, Bs, wave, lane);
    __syncthreads();
#pragma unroll
    for (int ks = 0; ks < 64; ks += 32){
      short8v af[4], bfv[NT];
#pragma unroll
      for (int mt=0; mt<4; ++mt)  af[mt]  = ldfrag_swz(As, wm*64 + mt*16 + c, g, ks);
#pragma unroll
      for (int nt=0; nt<NT; ++nt) bfv[nt] = ldfrag_swz(Bs, wn*(BN/2) + nt*16 + c, g, ks);
#pragma unroll
      for (int mt=0; mt<4; ++mt)
#pragma unroll
      for (int nt=0; nt<NT; ++nt)
        acc[mt][nt] = __builtin_amdgcn_mfma_f32_16x16x32_bf16(af[mt], bfv[nt], acc[mt][nt], 0, 0, 0);
    }
  }

#pragma unroll
  for (int mt=0; mt<4; ++mt)
#pragma unroll
  for (int nt=0; nt<NT; ++nt)
#pragma unroll
  for (int r=0; r<4; ++r){
    const int m = m0 + wm*64 + mt*16 + g*4 + r;
    const int nl = wn*(BN/2) + nt*16 + c;
    const float v = acc[mt][nt][r];
    if (MODE == 0){
      const int l = m >> 2, b = m & 3;
      if (isQ){
        const int n = n0 + nl, hh = n >> 6, d = n & 63;
        // 0.125 * log2(e): softmax done in exp2 space downstream
        ((ushort*)O0)[ (((size_t)(b*N_H + hh)*N_LQ + l) << 6) + permd(d) ] = f2bf(v * 0.18033688011112042f);
      } else {
        const int n = n0 + nl, hh = n >> 7, sv = (n >> 6) & 1, d = n & 63;
        if (sv == 0)
          ((ushort*)O1)[ (((size_t)(b*N_H + hh)*N_LK + l) << 6) + permd(d) ] = f2bf(v);
        else
          ((ushort*)O2)[ (((size_t)(b*N_H + hh)*N_DH + d) << 10) + (l & ~31) + permd(l & 31) ] = f2bf(v);
      }
    } else {
      ((float*)O0)[ (size_t)m*N_E + n0 + nl ] = v;
    }
  }
}

// ---- single-pass fused attention, P-in-LDS -------------------------------
// Block = 32 q-rows of one (b,h). k-loop computes S^T once per tile, keeps
// unnormalized P (bf16) in a 64 KB XOR-swizzled LDS buffer, accumulates
// unnormalized PV and row-sums; epilogue normalizes: cov as contiguous
// 512B/thread streams, ctx scaled by inv_l. K/V single-buffered (80 KB total,
// 2 blocks/CU), stages pipelined under the opposite compute phase.
__global__ __launch_bounds__(256) void attn_kernel(
    const ushort* __restrict__ qh, const ushort* __restrict__ kh,
    const ushort* __restrict__ vT, float* __restrict__ cov,
    ushort* __restrict__ ctx){
  __shared__ ushort P[32*1024];     // 64 KB  [32 q][1024 k] bf16, chunk-XOR swizzled
  __shared__ ushort Ks[64*64];      // 8 KB
  __shared__ ushort Vs[64*64];      // 8 KB
  const int tid  = threadIdx.x;
  const int lane = tid & 63, w = tid >> 6;       // w = wave = k-slice / d-slice owner
  const int g = lane >> 4, c = lane & 15;

  // T1: bh-contiguous chunks per XCD (8 heads/XCD)
  const int lin = blockIdx.y * 32 + blockIdx.x;  // grid (32, 64) = 2048
  const int swz = (lin & 7) * 256 + (lin >> 3);
  const int bh = swz >> 5, qb = swz & 31;

  const ushort* kbase = kh + (size_t)bh*N_LK*N_DH;
  const ushort* vbase = vT + (size_t)bh*N_DH*N_LK;

  // Q fragments (d-permuted rows -> contiguous b128); q pre-scaled by log2e/8
  short8v qf[2][2];
#pragma unroll
  for (int qt=0; qt<2; ++qt){
    const ushort* qrow = qh + ((size_t)bh*N_LQ + qb*32 + qt*16 + c)*N_DH;
    qf[qt][0] = *(const short8v*)(qrow + 8*g);
    qf[qt][1] = *(const short8v*)(qrow + 32 + 8*g);
  }

  stage_tile<2>(kbase, N_DH, Ks, w, lane);
  stage_tile<2>(vbase, N_LK, Vs, w, lane);
  __syncthreads();

  float lsum[2] = {0.f, 0.f};
  float4v cacc[2];
  cacc[0][0]=0.f; cacc[0][1]=0.f; cacc[0][2]=0.f; cacc[0][3]=0.f;
  cacc[1][0]=0.f; cacc[1][1]=0.f; cacc[1][2]=0.f; cacc[1][3]=0.f;

  const int pko   = (w<<4) + (g<<2);       // k-offset within tile for P write
  const int phalf = (pko & 7) << 1;        // byte sub-offset within 16B chunk

  for (int t = 0; t < 16; ++t){
    // ---- QK^T: wave w computes S^T rows k = t*64 + w*16 + (4g+r), q cols 32
    short8v kf0 = ldfrag_swz(Ks, (w<<4) + c, g, 0);
    short8v kf1 = ldfrag_swz(Ks, (w<<4) + c, g, 32);
#pragma unroll
    for (int qt=0; qt<2; ++qt){
      float4v s; s[0]=0.f; s[1]=0.f; s[2]=0.f; s[3]=0.f;
      s = __builtin_amdgcn_mfma_f32_16x16x32_bf16(kf0, qf[qt][0], s, 0, 0, 0);
      s = __builtin_amdgcn_mfma_f32_16x16x32_bf16(kf1, qf[qt][1], s, 0, 0, 0);
      float p0 = EXP2(s[0]), p1 = EXP2(s[1]), p2 = EXP2(s[2]), p3 = EXP2(s[3]);
      lsum[qt] += (p0 + p1) + (p2 + p3);
      short4v pw;
      pw[0] = (short)f2bf_n(p0); pw[1] = (short)f2bf_n(p1);
      pw[2] = (short)f2bf_n(p2); pw[3] = (short)f2bf_n(p3);
      const int row = (qt<<4) + c;
      const int ch  = (((t<<3) + (pko>>3)) ^ (row & 7));
      *(short4v*)((char*)P + row*2048 + (ch<<4) + phalf) = pw;
    }
    __syncthreads();                        // P(t) visible; Ks(t) consumed
    if (t < 15) stage_tile<2>(kbase + (size_t)(t+1)*64*N_DH, N_DH, Ks, w, lane);

    // ---- PV: wave w owns d-rows w*16+c; B = P^T from LDS
    short8v vf0 = ldfrag_swz(Vs, (w<<4) + c, g, 0);
    short8v vf1 = ldfrag_swz(Vs, (w<<4) + c, g, 32);
#pragma unroll
    for (int qt=0; qt<2; ++qt){
      const int row = (qt<<4) + c;
      const char* pr = (const char*)P + row*2048;
      const int ko0 = (t<<6) + (g<<2);
      const int c0 = ((ko0>>3)      ^ (row & 7));
      const int c1 = (((ko0+16)>>3) ^ (row & 7));
      const int c2 = (((ko0+32)>>3) ^ (row & 7));
      const int c3 = (((ko0+48)>>3) ^ (row & 7));
      short4v p0 = *(const short4v*)(pr + (c0<<4) + phalf);
      short4v p1 = *(const short4v*)(pr + (c1<<4) + phalf);
      short4v p2 = *(const short4v*)(pr + (c2<<4) + phalf);
      short4v p3 = *(const short4v*)(pr + (c3<<4) + phalf);
      short8v pfa, pfb;
      pfa[0]=p0[0]; pfa[1]=p0[1]; pfa[2]=p0[2]; pfa[3]=p0[3];
      pfa[4]=p1[0]; pfa[5]=p1[1]; pfa[6]=p1[2]; pfa[7]=p1[3];
      pfb[0]=p2[0]; pfb[1]=p2[1]; pfb[2]=p2[2]; pfb[3]=p2[3];
      pfb[4]=p3[0]; pfb[5]=p3[1]; pfb[6]=p3[2]; pfb[7]=p3[3];
      cacc[qt] = __builtin_amdgcn_mfma_f32_16x16x32_bf16(vf0, pfa, cacc[qt], 0, 0, 0);
      cacc[qt] = __builtin_amdgcn_mfma_f32_16x16x32_bf16(vf1, pfb, cacc[qt], 0, 0, 0);
    }
    __syncthreads();                        // Vs(t) consumed; Ks(t+1) staged
    if (t < 15) stage_tile<2>(vbase + (t+1)*64, N_LK, Vs, w, lane);
  }

  // ---- denominators: reduce over g, then across waves via LDS (reuse Ks)
  float* red = (float*)Ks;                  // [w][qt][c] = 4*2*16 floats
#pragma unroll
  for (int qt=0; qt<2; ++qt){
    lsum[qt] += __shfl_xor(lsum[qt], 16);
    lsum[qt] += __shfl_xor(lsum[qt], 32);
  }
  if (lane < 16){
    red[((w<<1) + 0)*16 + c] = lsum[0];
    red[((w<<1) + 1)*16 + c] = lsum[1];
  }
  __syncthreads();

  // ---- ctx: cacc (unnormalized) * inv_l; e-permuted rows, one b64 per qt
  {
    const int b = bh >> 4, hh = bh & 15;
    const int pos = ((w & 2) << 4) + ((w & 1) << 2) + (g << 3);
#pragma unroll
    for (int qt=0; qt<2; ++qt){
      const float linv = 1.0f / (red[(0 + qt)*16 + c] + red[(2 + qt)*16 + c]
                               + red[(4 + qt)*16 + c] + red[(6 + qt)*16 + c]);
      const int q = qb*32 + (qt<<4) + c;
      short4v o;
      o[0] = (short)f2bf_n(cacc[qt][0] * linv);
      o[1] = (short)f2bf_n(cacc[qt][1] * linv);
      o[2] = (short)f2bf_n(cacc[qt][2] * linv);
      o[3] = (short)f2bf_n(cacc[qt][3] * linv);
      *(short4v*)(ctx + (((size_t)q*N_B + b) << 10) + hh*N_DH + pos) = o;
    }
  }

  // ---- cov: stream P -> normalized f32, contiguous 512B per thread
  {
    const int row = tid >> 3;               // 32 rows, 8 threads per row
    const int cq = row & 15, qt = row >> 4;
    const float linv = 1.0f / (red[(0 + qt)*16 + cq] + red[(2 + qt)*16 + cq]
                             + red[(4 + qt)*16 + cq] + red[(6 + qt)*16 + cq]);
    const char* pr = (const char*)P + row*2048;
    float* crow = cov + ((size_t)bh*N_LQ + qb*32 + row)*N_LK + (tid & 7)*128;
    const int ch0 = (tid & 7) << 4;
#pragma unroll
    for (int j = 0; j < 16; ++j){
      short8v pv = *(const short8v*)(pr + (((ch0 + j) ^ (row & 7))<<4));
      float4v o0, o1;
#pragma unroll
      for (int r=0; r<4; ++r){
        o0[r] = __uint_as_float(((unsigned)(unsigned short)pv[r])   << 16) * linv;
        o1[r] = __uint_as_float(((unsigned)(unsigned short)pv[4+r]) << 16) * linv;
      }
      *(float4v*)(crow + j*8)     = o0;
      *(float4v*)(crow + j*8 + 4) = o1;
    }
  }
}

extern "C" void kernel_launch(void* const* d_in, const int* in_sizes, int n_in,
                              void* d_out, int out_size, void* d_ws, size_t ws_size,
                              hipStream_t stream){
  (void)in_sizes; (void)n_in; (void)out_size; (void)ws_size;
  const float* query = (const float*)d_in[0];
  const float* key   = (const float*)d_in[1];
  const float* Wq    = (const float*)d_in[2];
  const float* Wkv   = (const float*)d_in[3];
  const float* Wout  = (const float*)d_in[4];

  float* out = (float*)d_out;
  float* cov = out + (size_t)N_LQ*N_B*N_E;

  ushort* ws   = (ushort*)d_ws;
  ushort* qbf  = ws;                      // 4194304
  ushort* kbf  = qbf  + 4194304;          // 4194304
  ushort* wqb  = kbf  + 4194304;          // 1048576
  ushort* wkvb = wqb  + 1048576;          // 2097152
  ushort* wob  = wkvb + 2097152;          // 1048576
  ushort* qh   = wob  + 1048576;          // [b,h][lq][dh] (d-permuted), *log2e/8
  ushort* kh   = qh   + 4194304;          // [b,h][lk][dh] (d-permuted)
  ushort* vTp  = kh   + 4194304;          // [b,h][dh][lk] (l-permuted cols)
  ushort* ctx  = vTp  + 4194304;          // [(q*B+b)][e]  (e-permuted)

  cvt_all<<<6144, 256, 0, stream>>>(query, key, Wq, Wkv, Wout, qbf);
  gemm_k<0,128><<<dim3(32, 24), 256, 0, stream>>>(qbf, kbf, wqb, wkvb, qh, kh, vTp, N_E);
  attn_kernel<<<dim3(32, 64), 256, 0, stream>>>(qh, kh, vTp, cov, ctx);
  gemm_k<2,64><<<dim3(32, 16), 256, 0, stream>>>(ctx, nullptr, wob, nullptr, out, nullptr, nullptr, N_E);
}

// Round 12
// 155.101 us; speedup vs baseline: 1.4106x; 1.4106x over previous
//
#include <hip/hip_runtime.h>
#include <hip/hip_bf16.h>

typedef short  short4v __attribute__((ext_vector_type(4)));
typedef short  short8v __attribute__((ext_vector_type(8)));
typedef float  float4v __attribute__((ext_vector_type(4)));

#define N_LQ 1024
#define N_LK 1024
#define N_B  4
#define N_E  1024
#define N_H  16
#define N_DH 64

#define EXP2(x) __builtin_amdgcn_exp2f(x)

// counted-vmcnt tile barrier: retire staging loads (oldest in FIFO), leave the
// newest N vmem ops (this iter's cov stores) in flight. No sched_barrier (m141).
#define TILE_BARRIER(N) do {                                  \
  asm volatile("s_waitcnt vmcnt(" #N ")" ::: "memory");       \
  __builtin_amdgcn_s_barrier();                               \
} while (0)

__device__ __forceinline__ unsigned short f2bf(float f){
  unsigned int u = __float_as_uint(f);
  u += 0x7fffu + ((u >> 16) & 1u);          // round-to-nearest-even
  return (unsigned short)(u >> 16);
}

__device__ __forceinline__ ushort f2bf_n(float f){
  __hip_bfloat16 h = __float2bfloat16(f);
  return *reinterpret_cast<ushort*>(&h);
}

// permuted position of k-offset d within a 64-col row (k-blocks of 32):
// fragment chunk 8g holds k = 4g + (e&3) + 16*(e>>2)  -> contiguous b128 frags
__device__ __forceinline__ int permd(int d){
  return (d & 32) + 8*((d>>2)&3) + (d&3) + 4*((d>>4)&1);
}

__device__ __forceinline__ void gload_lds16(const void* g, void* lds){
  __builtin_amdgcn_global_load_lds(
      (const __attribute__((address_space(1))) unsigned int*)g,
      (__attribute__((address_space(3))) unsigned int*)lds, 16, 0, 0);
}

// Stage a (ROUNDS*32) x 64 bf16 tile (k-permuted layout) into linear LDS,
// T2 XOR-swizzle applied on the GLOBAL side at 16B-chunk granularity.
template<int ROUNDS>
__device__ __forceinline__ void stage_tile(const ushort* src, int lda, ushort* ldsbase,
                                           int wave, int lane){
  const int rl = lane >> 3;
  const int ch = lane & 7;
#pragma unroll
  for (int r = 0; r < ROUNDS; ++r){
    const int row = r*32 + wave*8 + rl;
    const int c   = ch ^ (row & 7);
    gload_lds16(src + (size_t)row*lda + c*8, ldsbase + (size_t)(r*32 + wave*8)*64);
  }
}

// One contiguous b128 fragment read from the swizzled k-permuted LDS tile.
__device__ __forceinline__ short8v ldfrag_swz(const ushort* tile, int row, int g, int ks){
  const int ch = ((ks >> 3) + g) ^ (row & 7);
  return *(const short8v*)(tile + row*64 + ch*8);
}

// ---- convert all five f32 inputs to bf16, k-permuted, in one pass ----------
__global__ __launch_bounds__(256) void cvt_all(
    const float* __restrict__ q, const float* __restrict__ k,
    const float* __restrict__ wq, const float* __restrict__ wkv,
    const float* __restrict__ wo, ushort* __restrict__ dst){
  const size_t i = ((size_t)blockIdx.x*256 + threadIdx.x)*8;
  const float* s; size_t o;
  if      (i <  4194304ull){ s = q;   o = i; }
  else if (i <  8388608ull){ s = k;   o = i -  4194304ull; }
  else if (i <  9437184ull){ s = wq;  o = i -  8388608ull; }
  else if (i < 11534336ull){ s = wkv; o = i -  9437184ull; }
  else                     { s = wo;  o = i - 11534336ull; }
  const size_t base = o & ~(size_t)31;
  const int g = (int)((o >> 3) & 3);
  float4v a = *(const float4v*)(s + base + 4*g);
  float4v b = *(const float4v*)(s + base + 4*g + 16);
  short8v r;
  r[0]=(short)f2bf(a[0]); r[1]=(short)f2bf(a[1]); r[2]=(short)f2bf(a[2]); r[3]=(short)f2bf(a[3]);
  r[4]=(short)f2bf(b[0]); r[5]=(short)f2bf(b[1]); r[6]=(short)f2bf(b[2]); r[7]=(short)f2bf(b[3]);
  *(short8v*)(dst + i) = r;
}

// ---- GEMM:  C[m][n] = sum_k A[m][k]*W[n][k], k-permuted inputs -------------
// MODE 0: fused QKV (panel<8 -> Q-proj, else KV-proj). MODE 2: out-proj.
template<int MODE, int BN>
__global__ __launch_bounds__(256) void gemm_k(
    const ushort* __restrict__ A0, const ushort* __restrict__ A1,
    const ushort* __restrict__ W0, const ushort* __restrict__ W1,
    void* __restrict__ O0, void* __restrict__ O1, void* __restrict__ O2,
    int K){
  __shared__ ushort As[128*64];
  __shared__ ushort Bs[BN*64];
  constexpr int NT = BN/32;
  const int tid = threadIdx.x, lane = tid & 63, wave = tid >> 6;
  const int g = lane >> 4, c = lane & 15;
  const int wm = wave >> 1, wn = wave & 1;

  // T1 XCD-aware swizzle (grid count divisible by 8)
  const int nx = gridDim.x;
  const int lin = blockIdx.y * nx + blockIdx.x;
  const int cpx = (nx * gridDim.y) >> 3;
  const int swz = (lin & 7) * cpx + (lin >> 3);
  const int bx = swz % nx, by = swz / nx;
  const int m0 = bx * 128;

  const ushort* A; const ushort* W; int n0; bool isQ = true;
  if (MODE == 0){
    isQ = by < 8;
    A = isQ ? A0 : A1; W = isQ ? W0 : W1;
    n0 = isQ ? by*128 : (by-8)*128;
  } else {
    A = A0; W = W0; n0 = by * BN;
  }

  float4v acc[4][NT];
#pragma unroll
  for (int i=0;i<4;i++)
#pragma unroll
  for (int j=0;j<NT;j++){ acc[i][j][0]=0.f; acc[i][j][1]=0.f; acc[i][j][2]=0.f; acc[i][j][3]=0.f; }

  for (int k0 = 0; k0 < K; k0 += 64){
    __syncthreads();
    stage_tile<4>     (A + (size_t)m0*K + k0, K, As, wave, lane);
    stage_tile<BN/32> (W + (size_t)n0*K + k0, K, Bs, wave, lane);
    __syncthreads();
#pragma unroll
    for (int ks = 0; ks < 64; ks += 32){
      short8v af[4], bfv[NT];
#pragma unroll
      for (int mt=0; mt<4; ++mt)  af[mt]  = ldfrag_swz(As, wm*64 + mt*16 + c, g, ks);
#pragma unroll
      for (int nt=0; nt<NT; ++nt) bfv[nt] = ldfrag_swz(Bs, wn*(BN/2) + nt*16 + c, g, ks);
#pragma unroll
      for (int mt=0; mt<4; ++mt)
#pragma unroll
      for (int nt=0; nt<NT; ++nt)
        acc[mt][nt] = __builtin_amdgcn_mfma_f32_16x16x32_bf16(af[mt], bfv[nt], acc[mt][nt], 0, 0, 0);
    }
  }

#pragma unroll
  for (int mt=0; mt<4; ++mt)
#pragma unroll
  for (int nt=0; nt<NT; ++nt)
#pragma unroll
  for (int r=0; r<4; ++r){
    const int m = m0 + wm*64 + mt*16 + g*4 + r;
    const int nl = wn*(BN/2) + nt*16 + c;
    const float v = acc[mt][nt][r];
    if (MODE == 0){
      const int l = m >> 2, b = m & 3;
      if (isQ){
        const int n = n0 + nl, hh = n >> 6, d = n & 63;
        // 0.125 * log2(e): softmax done in exp2 space downstream
        ((ushort*)O0)[ (((size_t)(b*N_H + hh)*N_LQ + l) << 6) + permd(d) ] = f2bf(v * 0.18033688011112042f);
      } else {
        const int n = n0 + nl, hh = n >> 7, sv = (n >> 6) & 1, d = n & 63;
        if (sv == 0)
          ((ushort*)O1)[ (((size_t)(b*N_H + hh)*N_LK + l) << 6) + permd(d) ] = f2bf(v);
        else
          ((ushort*)O2)[ (((size_t)(b*N_H + hh)*N_DH + d) << 10) + (l & ~31) + permd(l & 31) ] = f2bf(v);
      }
    } else {
      ((float*)O0)[ (size_t)m*N_E + n0 + nl ] = v;
    }
  }
}

// ---- fused attention: r10 structure, Q2=1, grid 16x64 = 4 blocks/CU --------
template<int Q2>
__global__ __launch_bounds__(256) void attn_kernel(
    const ushort* __restrict__ qh, const ushort* __restrict__ kh,
    const ushort* __restrict__ vT, float* __restrict__ cov,
    ushort* __restrict__ ctx){
  __shared__ ushort Ks[2][64*64];
  __shared__ ushort Vs[2][64*64];
  const int tid  = threadIdx.x;
  const int lane = tid & 63, wave = tid >> 6;
  const int g = lane >> 4, c = lane & 15;

  // T1: bh-contiguous chunks per XCD (8 heads/XCD -> 2 MB K+V < 4 MB L2)
  const int nx = gridDim.x;
  const int lin = blockIdx.y * nx + blockIdx.x;
  const int cpx = (nx * gridDim.y) >> 3;
  const int swz = (lin & 7) * cpx + (lin >> 3);
  const int bh = swz / nx, qb = swz % nx;

  const ushort* kbase = kh + (size_t)bh*N_LK*N_DH;
  const ushort* vbase = vT + (size_t)bh*N_DH*N_LK;

  // Q fragments (permuted layout -> contiguous b128); q pre-scaled by log2e/8
  short8v qf[Q2][2];
#pragma unroll
  for (int qt=0; qt<Q2; ++qt){
    const ushort* qbase = qh + ((size_t)bh*N_LQ + qb*(64*Q2) + qt*64 + wave*16 + c)*N_DH;
    qf[qt][0] = *(const short8v*)(qbase + 8*g);
    qf[qt][1] = *(const short8v*)(qbase + 32 + 8*g);
  }

  // ---- pass 1: denominators only (no max tracking; |S·log2e| < 9 ≪ 126)
  float lrun[Q2];
#pragma unroll
  for (int qt=0; qt<Q2; ++qt) lrun[qt] = 0.f;

  stage_tile<2>(kbase, N_DH, Ks[0], wave, lane);
  __syncthreads();
  int cur = 0;
  for (int t = 0; t < 16; ++t){
    if (t < 15) stage_tile<2>(kbase + (size_t)(t+1)*64*N_DH, N_DH, Ks[cur^1], wave, lane);
#pragma unroll
    for (int kt=0; kt<4; ++kt){
      short8v kf0 = ldfrag_swz(Ks[cur], kt*16 + c, g, 0);
      short8v kf1 = ldfrag_swz(Ks[cur], kt*16 + c, g, 32);
#pragma unroll
      for (int qt=0; qt<Q2; ++qt){
        float4v s; s[0]=0.f; s[1]=0.f; s[2]=0.f; s[3]=0.f;
        s = __builtin_amdgcn_mfma_f32_16x16x32_bf16(kf0, qf[qt][0], s, 0, 0, 0);
        s = __builtin_amdgcn_mfma_f32_16x16x32_bf16(kf1, qf[qt][1], s, 0, 0, 0);
        lrun[qt] += EXP2(s[0]) + EXP2(s[1]) + EXP2(s[2]) + EXP2(s[3]);
      }
    }
    __syncthreads();
    cur ^= 1;
  }

  // prefetch pass-2 tile 0 while combining denominators across lane groups
  stage_tile<2>(kbase, N_DH, Ks[0], wave, lane);
  stage_tile<2>(vbase, N_LK, Vs[0], wave, lane);

  float inv_l[Q2];
#pragma unroll
  for (int qt=0; qt<Q2; ++qt){
    lrun[qt] += __shfl_xor(lrun[qt], 16);
    lrun[qt] += __shfl_xor(lrun[qt], 32);
    inv_l[qt] = 1.0f / lrun[qt];
  }
  __syncthreads();

  // ---- pass 2: recompute S, coverage stores, PV accumulate
  float4v cacc[Q2][4];
#pragma unroll
  for (int qt=0; qt<Q2; ++qt)
#pragma unroll
  for (int dt=0; dt<4; ++dt){ cacc[qt][dt][0]=0.f; cacc[qt][dt][1]=0.f; cacc[qt][dt][2]=0.f; cacc[qt][dt][3]=0.f; }

  cur = 0;
  for (int t = 0; t < 16; ++t){
    if (t < 15){
      stage_tile<2>(kbase + (size_t)(t+1)*64*N_DH, N_DH, Ks[cur^1], wave, lane);  // 4 loads
      stage_tile<2>(vbase + (t+1)*64,              N_LK, Vs[cur^1], wave, lane);
    }
    float4v S[Q2][4];
#pragma unroll
    for (int kt=0; kt<4; ++kt){
      short8v kf0 = ldfrag_swz(Ks[cur], kt*16 + c, g, 0);
      short8v kf1 = ldfrag_swz(Ks[cur], kt*16 + c, g, 32);
#pragma unroll
      for (int qt=0; qt<Q2; ++qt){
        float4v s; s[0]=0.f; s[1]=0.f; s[2]=0.f; s[3]=0.f;
        s = __builtin_amdgcn_mfma_f32_16x16x32_bf16(kf0, qf[qt][0], s, 0, 0, 0);
        S[qt][kt] = __builtin_amdgcn_mfma_f32_16x16x32_bf16(kf1, qf[qt][1], s, 0, 0, 0);
      }
    }
    short8v pf[Q2][2];
#pragma unroll
    for (int qt=0; qt<Q2; ++qt){
      float* crow = cov + ((size_t)bh*N_LQ + qb*(64*Q2) + qt*64 + wave*16 + c)*N_LK + 4*g + t*64;
#pragma unroll
      for (int kt=0; kt<4; ++kt){
        float4v pv;
#pragma unroll
        for (int r=0; r<4; ++r) pv[r] = EXP2(S[qt][kt][r]) * inv_l[qt];
        S[qt][kt] = pv;
        *(float4v*)(crow + kt*16) = pv;                                            // 4*Q2 stores
      }
#pragma unroll
      for (int k2=0; k2<2; ++k2)
#pragma unroll
      for (int j=0; j<8; ++j) pf[qt][k2][j] = (short)f2bf_n(S[qt][2*k2 + (j>>2)][j&3]);
    }
#pragma unroll
    for (int k2=0; k2<2; ++k2)
#pragma unroll
    for (int dt=0; dt<4; ++dt){
      short8v vf = ldfrag_swz(Vs[cur], dt*16 + c, g, k2*32);
#pragma unroll
      for (int qt=0; qt<Q2; ++qt)
        cacc[qt][dt] = __builtin_amdgcn_mfma_f32_16x16x32_bf16(vf, pf[qt][k2], cacc[qt][dt], 0, 0, 0);
    }
    // retire the 4 staging loads (oldest); leave this iter's cov stores in flight
    if (t < 15){
      if constexpr (Q2 == 1) TILE_BARRIER(4); else TILE_BARRIER(8);
    } else __syncthreads();
    cur ^= 1;
  }

  // ---- epilogue: lane holds ctx^T[d=dt*16+4g+r][q]; permuted-e ctx, 16B stores
  {
    const int b = bh >> 4, hh = bh & 15;
#pragma unroll
    for (int qt=0; qt<Q2; ++qt){
      const int q = qb*(64*Q2) + qt*64 + wave*16 + c;
      ushort* dst = ctx + ((size_t)q*N_B + b)*N_E + hh*N_DH;
#pragma unroll
      for (int m2=0; m2<2; ++m2){
        short8v o;
#pragma unroll
        for (int r=0; r<4; ++r){
          o[r]   = (short)f2bf_n(cacc[qt][2*m2][r]);
          o[4+r] = (short)f2bf_n(cacc[qt][2*m2+1][r]);
        }
        *(short8v*)(dst + m2*32 + 8*g) = o;
      }
    }
  }
}

extern "C" void kernel_launch(void* const* d_in, const int* in_sizes, int n_in,
                              void* d_out, int out_size, void* d_ws, size_t ws_size,
                              hipStream_t stream){
  (void)in_sizes; (void)n_in; (void)out_size; (void)ws_size;
  const float* query = (const float*)d_in[0];
  const float* key   = (const float*)d_in[1];
  const float* Wq    = (const float*)d_in[2];
  const float* Wkv   = (const float*)d_in[3];
  const float* Wout  = (const float*)d_in[4];

  float* out = (float*)d_out;
  float* cov = out + (size_t)N_LQ*N_B*N_E;

  ushort* ws   = (ushort*)d_ws;
  ushort* qbf  = ws;                      // 4194304
  ushort* kbf  = qbf  + 4194304;          // 4194304
  ushort* wqb  = kbf  + 4194304;          // 1048576
  ushort* wkvb = wqb  + 1048576;          // 2097152
  ushort* wob  = wkvb + 2097152;          // 1048576
  ushort* qh   = wob  + 1048576;          // [b,h][lq][dh] (d-permuted), *log2e/8
  ushort* kh   = qh   + 4194304;          // [b,h][lk][dh] (d-permuted)
  ushort* vTp  = kh   + 4194304;          // [b,h][dh][lk] (l-permuted cols)
  ushort* ctx  = vTp  + 4194304;          // [(q*B+b)][e]  (e-permuted)

  cvt_all<<<6144, 256, 0, stream>>>(query, key, Wq, Wkv, Wout, qbf);
  gemm_k<0,128><<<dim3(32, 24), 256, 0, stream>>>(qbf, kbf, wqb, wkvb, qh, kh, vTp, N_E);
  attn_kernel<1><<<dim3(16, 64), 256, 0, stream>>>(qh, kh, vTp, cov, ctx);
  gemm_k<2,64><<<dim3(32, 16), 256, 0, stream>>>(ctx, nullptr, wob, nullptr, out, nullptr, nullptr, N_E);
}